// Round 5
// baseline (337.945 us; speedup 1.0000x reference)
//
#include <hip/hip_runtime.h>

#define NBATCH 4
#define NN 2048
#define NR 8192            // NBATCH*NN rows
#define TOPK 10
#define COLSW 2054         // vt row stride in halfwords = 1027 words (odd -> conflict-free)

typedef __attribute__((ext_vector_type(16))) float f32x16;
typedef __attribute__((ext_vector_type(8))) short bf16x8;

__device__ inline unsigned short f2bf(float x) {
    unsigned u = __float_as_uint(x);
    unsigned r = (u + 0x7FFF + ((u >> 16) & 1)) >> 16;
    return (unsigned short)r;
}

// ---------------- K1: encoders + fusion + q/k projection (bf16, dense 16-dim)
// Also zero-fills the CSR row counters (blocks 0..31) before k2b counts.
__global__ __launch_bounds__(256) void k1_encode(
    const float* __restrict__ xd, const float* __restrict__ xs,
    const float* __restrict__ Wd, const float* __restrict__ bd,
    const float* __restrict__ Ws, const float* __restrict__ bs,
    const float* __restrict__ Wf, const float* __restrict__ bf,
    const float* __restrict__ Wq, const float* __restrict__ Wk,
    unsigned short* __restrict__ qh, unsigned short* __restrict__ kh,
    unsigned* __restrict__ cnt)
{
    if (blockIdx.x < 32) cnt[blockIdx.x * 256 + threadIdx.x] = 0u;

    int wave = threadIdx.x >> 6;
    int lane = threadIdx.x & 63;
    int r = blockIdx.x * 4 + wave;        // 0..8191

    __shared__ float xm[4][16];
    __shared__ float xst[4][8];
    __shared__ float hc[4][128];
    __shared__ float hh[4][64];

    const float* xdr = xd + (size_t)r * 512;
    float acc = 0.f;
    #pragma unroll
    for (int j = 0; j < 8; ++j) acc += xdr[lane + 64*j];
    acc += __shfl_xor(acc, 16);
    acc += __shfl_xor(acc, 32);
    if (lane < 16) xm[wave][lane] = acc * (1.0f/32.0f);
    if (lane < 8)  xst[wave][lane] = xs[(size_t)r*8 + lane];
    __syncthreads();

    float a1 = bd[lane];
    #pragma unroll
    for (int d = 0; d < 16; ++d) a1 += xm[wave][d] * Wd[d*64 + lane];
    a1 = fmaxf(a1, 0.f);
    float a2 = bs[lane];
    #pragma unroll
    for (int d = 0; d < 8; ++d) a2 += xst[wave][d] * Ws[d*64 + lane];
    a2 = fmaxf(a2, 0.f);
    hc[wave][lane] = a1;
    hc[wave][64 + lane] = a2;
    __syncthreads();

    // 4 accumulators: break the 128-long fma dependency chain
    float hv0 = bf[lane], hv1 = 0.f, hv2 = 0.f, hv3 = 0.f;
    #pragma unroll
    for (int j = 0; j < 128; j += 4) {
        hv0 += hc[wave][j]   * Wf[(j)*64   + lane];
        hv1 += hc[wave][j+1] * Wf[(j+1)*64 + lane];
        hv2 += hc[wave][j+2] * Wf[(j+2)*64 + lane];
        hv3 += hc[wave][j+3] * Wf[(j+3)*64 + lane];
    }
    hh[wave][lane] = (hv0 + hv1) + (hv2 + hv3);
    __syncthreads();

    float qv0 = 0.f, qv1 = 0.f, kv0 = 0.f, kv1 = 0.f;
    #pragma unroll
    for (int j = 0; j < 64; j += 2) {
        float h0 = hh[wave][j], h1 = hh[wave][j+1];
        qv0 += h0 * Wq[(j)*64   + lane];
        qv1 += h1 * Wq[(j+1)*64 + lane];
        kv0 += h0 * Wk[(j)*64   + lane];
        kv1 += h1 * Wk[(j+1)*64 + lane];
    }
    float qv = qv0 + qv1, kv = kv0 + kv1;
    // lane = head*16 + dim; dense layout qh[(b*4+h)*2048 + n][16]
    int b = r >> 11, n = r & 2047;
    int head = lane >> 4, dim = lane & 15;
    size_t base = ((size_t)(b*4 + head) * NN + n) * 16;
    qh[base + dim] = f2bf(qv);
    kh[base + dim] = f2bf(kv);
}

// ---------------- K2A: softmax denominators via 32x32x16 MFMA (K=16, dense) -
// Swapped operands: A = K-tile, B = Q-tile -> q-row = lane&31, per-lane
// softmax sum is a scalar. No max machinery (scores ~N(0,1), no overflow).
__global__ __launch_bounds__(256) void k2a_stats(
    const unsigned short* __restrict__ qh, const unsigned short* __restrict__ kh,
    float* __restrict__ Rf)
{
    const float C1 = 0.36067376022224085f;   // 0.25 * log2(e)
    int bh = blockIdx.x >> 6;                // 16 (b,h) pairs
    int rg = blockIdx.x & 63;                // row group of 32
    int w = threadIdx.x >> 6, l = threadIdx.x & 63;
    int row = l & 31, khalf = l >> 5;

    bf16x8 qfrag = *(const bf16x8*)(qh + ((size_t)bh * NN + rg*32 + row) * 16 + khalf*8);
    const unsigned short* kbase = kh + (size_t)bh * NN * 16;

    __shared__ float redS[4][32];

    float Sloc = 0.f;
    for (int t = 0; t < 16; ++t) {           // 512-col strip per wave
        int m0 = w*512 + t*32;
        bf16x8 kfrag = *(const bf16x8*)(kbase + (size_t)(m0 + row) * 16 + khalf*8);
        f32x16 acc = {0.f,0.f,0.f,0.f,0.f,0.f,0.f,0.f,0.f,0.f,0.f,0.f,0.f,0.f,0.f,0.f};
        acc = __builtin_amdgcn_mfma_f32_32x32x16_bf16(kfrag, qfrag, acc, 0, 0, 0);
        #pragma unroll
        for (int rr = 0; rr < 16; ++rr) Sloc += exp2f(acc[rr] * C1);
    }
    Sloc += __shfl_xor(Sloc, 32);            // combine the two khalf col-sets
    if (l < 32) redS[w][l] = Sloc;
    __syncthreads();
    if (threadIdx.x < 32) {
        float S = redS[0][threadIdx.x] + redS[1][threadIdx.x]
                + redS[2][threadIdx.x] + redS[3][threadIdx.x];
        Rf[(size_t)bh * NN + rg*32 + threadIdx.x] = 1.0f / S;
    }
}

// ---------------- K2B: head-avg values (32x32x16) + top-10 -> compact winners
// No global scatter: winners stored as {wv_f32, r(13b), j(11b)} u64; per-dest
// CSR row counters bumped (own row: +TOPK once; symmetric: +1 per winner).
__global__ __launch_bounds__(1024, 4) void k2b_topk(
    const unsigned short* __restrict__ qh, const unsigned short* __restrict__ kh,
    const float* __restrict__ Rf,
    unsigned long long* __restrict__ winners, unsigned* __restrict__ cnt)
{
    const float C1 = 0.36067376022224085f;   // 0.25 * log2(e)
    int b  = blockIdx.x >> 6;
    int rg = blockIdx.x & 63;                // row group of 32
    int tid = threadIdx.x;
    int w = tid >> 6, l = tid & 63;
    int row = l & 31, khalf = l >> 5;

    __shared__ unsigned short vt[32][COLSW]; // bf16 values, odd-word stride

    bf16x8 qfrag[4];
    float r4[4];
    #pragma unroll
    for (int h = 0; h < 4; ++h) {
        int bh = b*4 + h;
        qfrag[h] = *(const bf16x8*)(qh + ((size_t)bh * NN + rg*32 + row) * 16 + khalf*8);
        r4[h] = Rf[(size_t)bh * NN + rg*32 + row] * 0.25f;
    }

    // ---- phase 2: combined values -> vt; wave strip = 128 cols (4 tiles)
    for (int t = 0; t < 4; ++t) {
        int m0 = w*128 + t*32;
        float vacc[16];
        #pragma unroll
        for (int rr = 0; rr < 16; ++rr) vacc[rr] = 0.f;
        #pragma unroll
        for (int h = 0; h < 4; ++h) {
            bf16x8 kfrag = *(const bf16x8*)(kh + ((size_t)(b*4+h) * NN + m0 + row) * 16 + khalf*8);
            f32x16 acc = {0.f,0.f,0.f,0.f,0.f,0.f,0.f,0.f,0.f,0.f,0.f,0.f,0.f,0.f,0.f,0.f};
            acc = __builtin_amdgcn_mfma_f32_32x32x16_bf16(kfrag, qfrag[h], acc, 0, 0, 0);
            #pragma unroll
            for (int rr = 0; rr < 16; ++rr)
                vacc[rr] = fmaf(exp2f(acc[rr] * C1), r4[h], vacc[rr]);
        }
        // cols: c(reg) = (reg&3) + 8*(reg>>2) + 4*khalf; reg pairs pack 2/b32
        #pragma unroll
        for (int p = 0; p < 8; ++p) {
            int reg0 = p*2;
            int c = m0 + ((reg0 & 3) + 8*(reg0 >> 2) + 4*khalf);
            unsigned pk = (unsigned)f2bf(vacc[reg0]) | ((unsigned)f2bf(vacc[reg0+1]) << 16);
            *(unsigned*)&vt[row][c] = pk;
        }
    }
    __syncthreads();

    // ---- phase 3: top-10, two rows per wave
    // keys packed in u32: (bf16_value << 16) | (2047 - col)  [lossless order]
    #pragma unroll 1
    for (int rr2 = 0; rr2 < 2; ++rr2) {
        int prow = w*2 + rr2;
        unsigned tk[TOPK];
        #pragma unroll
        for (int s = 0; s < TOPK; ++s) tk[s] = 0u;
        for (int j = 0; j < 16; ++j) {
            int m1 = 2*l + 128*j;
            unsigned pair = *(const unsigned*)&vt[prow][m1];
            unsigned key0 = (pair << 16)          | (unsigned)(2047 - m1);
            unsigned key1 = (pair & 0xFFFF0000u)  | (unsigned)(2046 - m1);
            if (key0 > tk[TOPK-1]) {
                unsigned ck = key0;
                #pragma unroll
                for (int s = 0; s < TOPK; ++s) {
                    bool ins = ck > tk[s];
                    unsigned o = tk[s];
                    tk[s] = ins ? ck : o;
                    ck    = ins ? o  : ck;
                }
            }
            if (key1 > tk[TOPK-1]) {
                unsigned ck = key1;
                #pragma unroll
                for (int s = 0; s < TOPK; ++s) {
                    bool ins = ck > tk[s];
                    unsigned o = tk[s];
                    tk[s] = ins ? ck : o;
                    ck    = ins ? o  : ck;
                }
            }
        }
        // 10 rounds of 64-lane argmax; lane s keeps round-s winner in a reg
        unsigned mykey = 0u;
        #pragma unroll 1
        for (int s = 0; s < TOPK; ++s) {
            unsigned kmax = tk[0];
            #pragma unroll
            for (int d = 1; d < 64; d <<= 1) {
                unsigned o = __shfl_xor(kmax, d);
                kmax = (o > kmax) ? o : kmax;
            }
            if (tk[0] == kmax) {   // exactly one winner pops its head
                #pragma unroll
                for (int q = 0; q < TOPK-1; ++q) tk[q] = tk[q+1];
                tk[TOPK-1] = 0u;
            }
            if (l == s) mykey = kmax;
        }

        // ---- phase 4: emit winner + CSR counts (no global scatter)
        int n = rg*32 + prow;
        int r = b*NN + n;                    // global dest row (own)
        if (l == 0) atomicAdd(&cnt[r], (unsigned)TOPK);
        if (l < TOPK) {
            float wv = 0.35f * __uint_as_float(mykey & 0xFFFF0000u);  // .7*.5*v
            unsigned j = 2047u - (mykey & 0x7FFu);
            unsigned rj = (unsigned)(b*NN) + j;
            atomicAdd(&cnt[rj], 1u);
            winners[(size_t)r * TOPK + l] =
                ((unsigned long long)__float_as_uint(wv) << 32)
                | ((unsigned)r << 11) | j;
        }
    }
}

// ---------------- KSCAN: exclusive prefix sum of cnt[8192] -> row_ptr, cursor
__global__ __launch_bounds__(1024) void kscan(
    const unsigned* __restrict__ cnt,
    unsigned* __restrict__ row_ptr, unsigned* __restrict__ cursor)
{
    int t = threadIdx.x;
    unsigned loc[8]; unsigned s = 0u;
    #pragma unroll
    for (int i = 0; i < 8; ++i) { loc[i] = s; s += cnt[t*8 + i]; }
    __shared__ unsigned ss[1024];
    ss[t] = s;
    __syncthreads();
    for (int off = 1; off < 1024; off <<= 1) {
        unsigned v = (t >= off) ? ss[t - off] : 0u;
        __syncthreads();
        ss[t] += v;
        __syncthreads();
    }
    unsigned base = ss[t] - s;               // exclusive offset
    #pragma unroll
    for (int i = 0; i < 8; ++i) {
        unsigned v = base + loc[i];
        row_ptr[t*8 + i] = v;
        cursor[t*8 + i]  = v;
    }
}

// ---------------- KPLACE: winners -> CSR entries (2 directed per winner) ----
__global__ __launch_bounds__(256) void kplace(
    const unsigned long long* __restrict__ winners,
    unsigned* __restrict__ cursor, unsigned long long* __restrict__ entries)
{
    int idx = blockIdx.x * 256 + threadIdx.x;   // 0..81919
    unsigned long long wp = winners[idx];
    unsigned lo = (unsigned)wp;
    unsigned r  = (lo >> 11) & 8191u;
    unsigned j  = lo & 2047u;
    unsigned long long hv = wp & 0xFFFFFFFF00000000ull;  // f32 bits of wv
    unsigned rj = (r & ~2047u) | j;
    unsigned s1 = atomicAdd(&cursor[r], 1u);
    entries[s1] = hv | j;
    unsigned s2 = atomicAdd(&cursor[rj], 1u);
    entries[s2] = hv | (r & 2047u);
}

// ---------------- K3F: stream prior -> A-row in LDS, apply CSR, write A & L -
// Atomic-free at global scope; every output line written exactly once.
__global__ __launch_bounds__(256) void k3_final(
    const float* __restrict__ prior,
    const unsigned* __restrict__ row_ptr, const unsigned* __restrict__ cnt,
    const unsigned long long* __restrict__ entries,
    float* __restrict__ Lout, float* __restrict__ Aout)
{
    int r = blockIdx.x;
    int tid = threadIdx.x;
    __shared__ float arow[NN];
    __shared__ float wsum[4];
    __shared__ float esum;
    if (tid == 0) esum = 0.f;

    const float4* pr = (const float4*)(prior + (size_t)r * NN);
    float sum = 0.f;
    for (int i = tid; i < NN/4; i += 256) {
        float4 p = pr[i];
        float4 a; a.x = 0.3f*p.x; a.y = 0.3f*p.y; a.z = 0.3f*p.z; a.w = 0.3f*p.w;
        *(float4*)&arow[4*i] = a;
        sum += a.x + a.y + a.z + a.w;
    }
    #pragma unroll
    for (int o = 32; o > 0; o >>= 1) sum += __shfl_down(sum, o);
    if ((tid & 63) == 0) wsum[tid >> 6] = sum;
    __syncthreads();

    unsigned c0 = cnt[r], st = row_ptr[r];
    for (unsigned t = tid; t < c0; t += 256) {
        unsigned long long e = entries[st + t];
        float wv = __uint_as_float((unsigned)(e >> 32));
        unsigned col = (unsigned)e & 2047u;
        atomicAdd(&arow[col], wv);     // LDS atomic (dedupes reciprocal picks)
        atomicAdd(&esum, wv);
    }
    __syncthreads();

    float deg = wsum[0] + wsum[1] + wsum[2] + wsum[3] + esum;
    int diag = r & 2047;
    float4* Ar = (float4*)(Aout + (size_t)r * NN);
    float4* Lr = (float4*)(Lout + (size_t)r * NN);
    for (int i = tid; i < NN/4; i += 256) {
        float4 a = *(const float4*)&arow[4*i];
        Ar[i] = a;
        float4 lv; lv.x = -a.x; lv.y = -a.y; lv.z = -a.z; lv.w = -a.w;
        if (i == (diag >> 2)) ((float*)&lv)[diag & 3] += deg;
        Lr[i] = lv;
    }
}

extern "C" void kernel_launch(void* const* d_in, const int* in_sizes, int n_in,
                              void* d_out, int out_size, void* d_ws, size_t ws_size,
                              hipStream_t stream)
{
    const float* xd    = (const float*)d_in[0];
    const float* xs    = (const float*)d_in[1];
    const float* prior = (const float*)d_in[2];
    const float* Wd    = (const float*)d_in[3];
    const float* bd    = (const float*)d_in[4];
    const float* Ws    = (const float*)d_in[5];
    const float* bs    = (const float*)d_in[6];
    const float* Wf    = (const float*)d_in[7];
    const float* bf    = (const float*)d_in[8];
    const float* Wq    = (const float*)d_in[9];
    const float* Wk    = (const float*)d_in[10];

    float* Lout = (float*)d_out;
    float* Aout = Lout + (size_t)NR * NN;

    unsigned short* qh = (unsigned short*)d_ws;              // 16*2048*16 bf16 = 1MB
    unsigned short* kh = qh + (size_t)16 * NN * 16;          // 1MB
    float* Rf  = (float*)(kh + (size_t)16 * NN * 16);        // 16*2048 f32 = 128KB
    unsigned* cnt     = (unsigned*)(Rf + (size_t)16 * NN);   // 8192 u32
    unsigned* row_ptr = cnt + NR;                            // 8192 u32
    unsigned* cursor  = row_ptr + NR;                        // 8192 u32
    unsigned long long* winners = (unsigned long long*)(cursor + NR);   // 81920 u64
    unsigned long long* entries = winners + (size_t)TOPK * NR;          // 163840 u64

    k1_encode<<<NR/4, 256, 0, stream>>>(xd, xs, Wd, bd, Ws, bs, Wf, bf, Wq, Wk, qh, kh, cnt);
    k2a_stats<<<16*64, 256, 0, stream>>>(qh, kh, Rf);
    k2b_topk<<<NBATCH*64, 1024, 0, stream>>>(qh, kh, Rf, winners, cnt);
    kscan<<<1, 1024, 0, stream>>>(cnt, row_ptr, cursor);
    kplace<<<TOPK*NR/256, 256, 0, stream>>>(winners, cursor, entries);
    k3_final<<<NR, 256, 0, stream>>>(prior, row_ptr, cnt, entries, Lout, Aout);
}

// Round 6
// 322.329 us; speedup vs baseline: 1.0484x; 1.0484x over previous
//
#include <hip/hip_runtime.h>

#define NBATCH 4
#define NN 2048
#define NR 8192            // NBATCH*NN rows
#define TOPK 10
#define COLSW 2054         // vt row stride in halfwords = 1027 words (odd -> conflict-free)

typedef __attribute__((ext_vector_type(16))) float f32x16;
typedef __attribute__((ext_vector_type(8))) short bf16x8;

__device__ inline unsigned short f2bf(float x) {
    unsigned u = __float_as_uint(x);
    unsigned r = (u + 0x7FFF + ((u >> 16) & 1)) >> 16;
    return (unsigned short)r;
}

// ---------------- K1: encoders + fusion + q/k projection (bf16, dense 16-dim)
__global__ __launch_bounds__(256) void k1_encode(
    const float* __restrict__ xd, const float* __restrict__ xs,
    const float* __restrict__ Wd, const float* __restrict__ bd,
    const float* __restrict__ Ws, const float* __restrict__ bs,
    const float* __restrict__ Wf, const float* __restrict__ bf,
    const float* __restrict__ Wq, const float* __restrict__ Wk,
    unsigned short* __restrict__ qh, unsigned short* __restrict__ kh)
{
    int wave = threadIdx.x >> 6;
    int lane = threadIdx.x & 63;
    int r = blockIdx.x * 4 + wave;        // 0..8191

    __shared__ float xm[4][16];
    __shared__ float xst[4][8];
    __shared__ float hc[4][128];
    __shared__ float hh[4][64];

    const float* xdr = xd + (size_t)r * 512;
    float acc = 0.f;
    #pragma unroll
    for (int j = 0; j < 8; ++j) acc += xdr[lane + 64*j];
    acc += __shfl_xor(acc, 16);
    acc += __shfl_xor(acc, 32);
    if (lane < 16) xm[wave][lane] = acc * (1.0f/32.0f);
    if (lane < 8)  xst[wave][lane] = xs[(size_t)r*8 + lane];
    __syncthreads();

    float a1 = bd[lane];
    #pragma unroll
    for (int d = 0; d < 16; ++d) a1 += xm[wave][d] * Wd[d*64 + lane];
    a1 = fmaxf(a1, 0.f);
    float a2 = bs[lane];
    #pragma unroll
    for (int d = 0; d < 8; ++d) a2 += xst[wave][d] * Ws[d*64 + lane];
    a2 = fmaxf(a2, 0.f);
    hc[wave][lane] = a1;
    hc[wave][64 + lane] = a2;
    __syncthreads();

    // 4 accumulators: break the 128-long fma dependency chain
    float hv0 = bf[lane], hv1 = 0.f, hv2 = 0.f, hv3 = 0.f;
    #pragma unroll
    for (int j = 0; j < 128; j += 4) {
        hv0 += hc[wave][j]   * Wf[(j)*64   + lane];
        hv1 += hc[wave][j+1] * Wf[(j+1)*64 + lane];
        hv2 += hc[wave][j+2] * Wf[(j+2)*64 + lane];
        hv3 += hc[wave][j+3] * Wf[(j+3)*64 + lane];
    }
    hh[wave][lane] = (hv0 + hv1) + (hv2 + hv3);
    __syncthreads();

    float qv0 = 0.f, qv1 = 0.f, kv0 = 0.f, kv1 = 0.f;
    #pragma unroll
    for (int j = 0; j < 64; j += 2) {
        float h0 = hh[wave][j], h1 = hh[wave][j+1];
        qv0 += h0 * Wq[(j)*64   + lane];
        qv1 += h1 * Wq[(j+1)*64 + lane];
        kv0 += h0 * Wk[(j)*64   + lane];
        kv1 += h1 * Wk[(j+1)*64 + lane];
    }
    float qv = qv0 + qv1, kv = kv0 + kv1;
    // lane = head*16 + dim; dense layout qh[(b*4+h)*2048 + n][16]
    int b = r >> 11, n = r & 2047;
    int head = lane >> 4, dim = lane & 15;
    size_t base = ((size_t)(b*4 + head) * NN + n) * 16;
    qh[base + dim] = f2bf(qv);
    kh[base + dim] = f2bf(kv);
}

// ---------------- K3: A base = 0.3*prior; L = -A; fold 0.3*rowsum into diag -
// (launched BEFORE k2b so the fused scatter lands on a complete base)
__global__ __launch_bounds__(256) void k3_base(
    const float* __restrict__ prior, float* __restrict__ Lout,
    float* __restrict__ Aout)
{
    int r = blockIdx.x;
    const float4* pr = (const float4*)(prior + (size_t)r * NN);
    float4* Ar = (float4*)(Aout + (size_t)r * NN);
    float4* Lr = (float4*)(Lout + (size_t)r * NN);
    float sum = 0.f;
    for (int i = threadIdx.x; i < NN/4; i += 256) {
        float4 p = pr[i];
        float4 a; a.x = 0.3f*p.x; a.y = 0.3f*p.y; a.z = 0.3f*p.z; a.w = 0.3f*p.w;
        Ar[i] = a;
        float4 lv; lv.x = -a.x; lv.y = -a.y; lv.z = -a.z; lv.w = -a.w;
        Lr[i] = lv;
        sum += a.x + a.y + a.z + a.w;
    }
    #pragma unroll
    for (int o = 32; o > 0; o >>= 1) sum += __shfl_down(sum, o);
    __shared__ float wsum[4];
    if ((threadIdx.x & 63) == 0) wsum[threadIdx.x >> 6] = sum;
    __syncthreads();
    if (threadIdx.x == 0) {
        float tot = wsum[0] + wsum[1] + wsum[2] + wsum[3];
        atomicAdd(&Lout[(size_t)r * NN + (r & 2047)], tot);
    }
}

// ---------------- K2: fused denominators + head-avg values + top-10 + scatter
// Phase 0 computes softmax denominators in-kernel (16 waves cover all 2048
// cols) -> no separate k2a launch, no Rf round-trip. Swapped operands
// (A=K-tile, B=Q-tile) put q-row = lane&31: per-lane softmax sum is a scalar.
// No max machinery (scores ~N(0,1); exp2(s*0.25*log2e) cannot overflow --
// validated passing in rounds 2-5).
__global__ __launch_bounds__(1024, 4) void k2_fused(
    const unsigned short* __restrict__ qh, const unsigned short* __restrict__ kh,
    float* __restrict__ Lout, float* __restrict__ Aout)
{
    const float C1 = 0.36067376022224085f;   // 0.25 * log2(e)
    int b  = blockIdx.x >> 6;
    int rg = blockIdx.x & 63;                // row group of 32
    int tid = threadIdx.x;
    int w = tid >> 6, l = tid & 63;
    int row = l & 31, khalf = l >> 5;

    __shared__ unsigned short vt[32][COLSW]; // bf16 values, odd-word stride (128.4KB)
    __shared__ float redS[16][4][32];        // [wave][head][row] partials (8KB)
    __shared__ float r4s[4][32];             // [head][row] 0.25/S

    bf16x8 qfrag[4];
    #pragma unroll
    for (int h = 0; h < 4; ++h)
        qfrag[h] = *(const bf16x8*)(qh + ((size_t)(b*4+h) * NN + rg*32 + row) * 16 + khalf*8);

    // ---- phase 0: per-(head,row) exp-sums; wave strip = 128 cols (4 tiles)
    float Sl[4] = {0.f, 0.f, 0.f, 0.f};
    for (int t = 0; t < 4; ++t) {
        int m0 = w*128 + t*32;
        #pragma unroll
        for (int h = 0; h < 4; ++h) {
            bf16x8 kfrag = *(const bf16x8*)(kh + ((size_t)(b*4+h) * NN + m0 + row) * 16 + khalf*8);
            f32x16 acc = {0.f,0.f,0.f,0.f,0.f,0.f,0.f,0.f,0.f,0.f,0.f,0.f,0.f,0.f,0.f,0.f};
            acc = __builtin_amdgcn_mfma_f32_32x32x16_bf16(kfrag, qfrag[h], acc, 0, 0, 0);
            #pragma unroll
            for (int rr = 0; rr < 16; ++rr) Sl[h] += exp2f(acc[rr] * C1);
        }
    }
    #pragma unroll
    for (int h = 0; h < 4; ++h) Sl[h] += __shfl_xor(Sl[h], 32);  // merge khalf halves
    if (l < 32) {
        #pragma unroll
        for (int h = 0; h < 4; ++h) redS[w][h][l] = Sl[h];
    }
    __syncthreads();
    if (tid < 128) {
        int h = tid >> 5, rw = tid & 31;
        float s = 0.f;
        #pragma unroll
        for (int ww = 0; ww < 16; ++ww) s += redS[ww][h][rw];
        r4s[h][rw] = 0.25f / s;
    }
    __syncthreads();

    float r4[4];
    #pragma unroll
    for (int h = 0; h < 4; ++h) r4[h] = r4s[h][row];

    // ---- phase 2: combined values -> vt; same sweep again (kh is L2-hot)
    for (int t = 0; t < 4; ++t) {
        int m0 = w*128 + t*32;
        float vacc[16];
        #pragma unroll
        for (int rr = 0; rr < 16; ++rr) vacc[rr] = 0.f;
        #pragma unroll
        for (int h = 0; h < 4; ++h) {
            bf16x8 kfrag = *(const bf16x8*)(kh + ((size_t)(b*4+h) * NN + m0 + row) * 16 + khalf*8);
            f32x16 acc = {0.f,0.f,0.f,0.f,0.f,0.f,0.f,0.f,0.f,0.f,0.f,0.f,0.f,0.f,0.f,0.f};
            acc = __builtin_amdgcn_mfma_f32_32x32x16_bf16(kfrag, qfrag[h], acc, 0, 0, 0);
            #pragma unroll
            for (int rr = 0; rr < 16; ++rr)
                vacc[rr] = fmaf(exp2f(acc[rr] * C1), r4[h], vacc[rr]);
        }
        // cols: c(reg) = (reg&3) + 8*(reg>>2) + 4*khalf; reg pairs pack 2/b32
        #pragma unroll
        for (int p = 0; p < 8; ++p) {
            int reg0 = p*2;
            int c = m0 + ((reg0 & 3) + 8*(reg0 >> 2) + 4*khalf);
            unsigned pk = (unsigned)f2bf(vacc[reg0]) | ((unsigned)f2bf(vacc[reg0+1]) << 16);
            *(unsigned*)&vt[row][c] = pk;
        }
    }
    __syncthreads();

    // ---- phase 3: top-10, two rows per wave
    // keys packed in u32: (bf16_value << 16) | (2047 - col)  [lossless order]
    #pragma unroll 1
    for (int rr2 = 0; rr2 < 2; ++rr2) {
        int prow = w*2 + rr2;
        unsigned tk[TOPK];
        #pragma unroll
        for (int s = 0; s < TOPK; ++s) tk[s] = 0u;
        for (int j = 0; j < 16; ++j) {
            int m1 = 2*l + 128*j;
            unsigned pair = *(const unsigned*)&vt[prow][m1];
            unsigned key0 = (pair << 16)          | (unsigned)(2047 - m1);
            unsigned key1 = (pair & 0xFFFF0000u)  | (unsigned)(2046 - m1);
            if (key0 > tk[TOPK-1]) {
                unsigned ck = key0;
                #pragma unroll
                for (int s = 0; s < TOPK; ++s) {
                    bool ins = ck > tk[s];
                    unsigned o = tk[s];
                    tk[s] = ins ? ck : o;
                    ck    = ins ? o  : ck;
                }
            }
            if (key1 > tk[TOPK-1]) {
                unsigned ck = key1;
                #pragma unroll
                for (int s = 0; s < TOPK; ++s) {
                    bool ins = ck > tk[s];
                    unsigned o = tk[s];
                    tk[s] = ins ? ck : o;
                    ck    = ins ? o  : ck;
                }
            }
        }
        // 10 rounds of 64-lane argmax; lane s keeps round-s winner in a reg
        unsigned mykey = 0u;
        #pragma unroll 1
        for (int s = 0; s < TOPK; ++s) {
            unsigned kmax = tk[0];
            #pragma unroll
            for (int d = 1; d < 64; d <<= 1) {
                unsigned o = __shfl_xor(kmax, d);
                kmax = (o > kmax) ? o : kmax;
            }
            if (tk[0] == kmax) {   // exactly one winner pops its head
                #pragma unroll
                for (int q = 0; q < TOPK-1; ++q) tk[q] = tk[q+1];
                tk[TOPK-1] = 0u;
            }
            if (l == s) mykey = kmax;
        }

        // ---- phase 4: symmetric scatter; own-diag pre-reduced to ONE atomic
        int n = rg*32 + prow;
        size_t rbase = (size_t)(b*NN + n) * NN;
        float wv = 0.f;
        int j = 0;
        if (l < TOPK) {
            wv = 0.35f * __uint_as_float(mykey & 0xFFFF0000u);  // 0.7*0.5*val
            j = 2047 - (int)(mykey & 0x7FFu);
        }
        // sum of the 10 winner weights (lanes 10..15 contribute 0)
        float swv = wv;
        #pragma unroll
        for (int d = 1; d <= 8; d <<= 1) swv += __shfl_xor(swv, d);
        if (l == 0) atomicAdd(&Lout[rbase + n], swv);   // deg[r] -> diag r
        if (l < TOPK) {
            size_t jbase = (size_t)(b*NN + j) * NN;
            atomicAdd(&Aout[rbase + j],  wv);
            atomicAdd(&Aout[jbase + n],  wv);
            atomicAdd(&Lout[rbase + j], -wv);
            atomicAdd(&Lout[jbase + n], -wv);
            atomicAdd(&Lout[jbase + j],  wv);           // deg[j] -> diag j
        }
    }
}

extern "C" void kernel_launch(void* const* d_in, const int* in_sizes, int n_in,
                              void* d_out, int out_size, void* d_ws, size_t ws_size,
                              hipStream_t stream)
{
    const float* xd    = (const float*)d_in[0];
    const float* xs    = (const float*)d_in[1];
    const float* prior = (const float*)d_in[2];
    const float* Wd    = (const float*)d_in[3];
    const float* bd    = (const float*)d_in[4];
    const float* Ws    = (const float*)d_in[5];
    const float* bs    = (const float*)d_in[6];
    const float* Wf    = (const float*)d_in[7];
    const float* bf    = (const float*)d_in[8];
    const float* Wq    = (const float*)d_in[9];
    const float* Wk    = (const float*)d_in[10];

    float* Lout = (float*)d_out;
    float* Aout = Lout + (size_t)NR * NN;

    unsigned short* qh = (unsigned short*)d_ws;          // 16*2048*16 bf16 = 1MB
    unsigned short* kh = qh + (size_t)16 * NN * 16;      // 1MB

    k1_encode<<<NR/4, 256, 0, stream>>>(xd, xs, Wd, bd, Ws, bs, Wf, bf, Wq, Wk, qh, kh);
    k3_base<<<NR, 256, 0, stream>>>(prior, Lout, Aout);
    k2_fused<<<NBATCH*64, 1024, 0, stream>>>(qh, kh, Lout, Aout);
}